// Round 1
// baseline (14611.493 us; speedup 1.0000x reference)
//
#include <hip/hip_runtime.h>
#include <math.h>

#define TT 2048
#define NB 64
#define EE 256
#define HH 256
#define PJ 16    // j-partitions recorded in part[] (unchanged layout)
#define XLD 288  // swizzled row: 256 + 4 pad per 32 floats

__device__ __forceinline__ float sigf(float x) { return 1.f / (1.f + expf(-x)); }

__device__ __forceinline__ unsigned long long packh(unsigned tag, float v) {
    union { float f; unsigned u; } c; c.f = v;
    return ((unsigned long long)tag << 32) | (unsigned long long)c.u;
}

// R7: dual-context staggered persistent LSTM.
// 32 groups x 2 batches; each WG serves (group g, slice s) AND (group g+16,
// slice s) -- same 16-j slice => same weight registers. While context A's
// handshake is in flight, the WG computes context B's half-step. h-tag loads
// pre-issued one half early; x goes emb->VGPR (no LDS staging); reduce+gates
// fused into role waves (wave0=A epilogue, wave1=B epilogue) in registers.
// All fp op orders per output value identical to the previous passing kernel
// (bitwise pz preservation).
__global__ __launch_bounds__(256, 1)
void lstm_kernel(const int* __restrict__ sent, const float* __restrict__ emb,
                 const float* __restrict__ W_ih, const float* __restrict__ W_hh,
                 const float* __restrict__ b_ih, const float* __restrict__ b_hh,
                 const float* __restrict__ W_z,
                 unsigned long long* __restrict__ hbuf,
                 float* __restrict__ part)
{
    __shared__ float h_swA[2 * XLD];
    __shared__ float h_swB[2 * XLD];
    __shared__ float red_s[8 * 132];   // [kc]*132 + [b]*64 + row(0..63)

    const int tid  = threadIdx.x;
    // XCD-clustering: a pair-system's 16 WGs land on one XCD (heuristic).
    const int xcd  = blockIdx.x & 7;
    const int slot = blockIdx.x >> 3;        // 0..31
    const int psys = xcd * 2 + (slot >> 4);  // 0..15 pair-system
    const int js   = slot & 15;              // j-slice 0..15
    const int b0A  = psys * 2;               // group gA = psys   -> batches
    const int b0B  = psys * 2 + 32;          // group gB = psys+16
    const int j0   = js * 16;

    const int wv    = tid >> 6;
    const int lane  = tid & 63;
    const int rg    = lane >> 2;             // 0..15 (4 rows each)
    const int klow  = lane & 3;
    const int kc    = (wv >> 1) * 4 + klow;  // 0..7 (32-float k chunk)
    const int bp    = wv & 1;                // batch within 2-batch group
    const int kbase = kc << 5;

    // ---- weights -> VGPRs (shared by both contexts: same j-slice) ----
    float4 wih_r[32], whh_r[32];
    #pragma unroll
    for (int i = 0; i < 4; ++i) {
        int lr = rg * 4 + i;                              // row 0..63
        long grow = (long)((lr >> 4) * HH + j0 + (lr & 15));
        const float4* wi = (const float4*)(W_ih + grow * EE + kbase);
        const float4* wh = (const float4*)(W_hh + grow * EE + kbase);
        #pragma unroll
        for (int mi = 0; mi < 8; ++mi) {
            wih_r[i * 8 + mi] = wi[mi];
            whh_r[i * 8 + mi] = wh[mi];
        }
    }

    // role lanes: wave0 lanes<32 -> A epilogue; wave1 lanes<32 -> B epilogue
    const bool roleA = (tid < 32);
    const bool roleB = (tid >= 64 && tid < 96);
    const int  rr  = roleA ? tid : (roleB ? tid - 64 : 0);
    const int  rb  = rr >> 4;     // batch 0..1
    const int  rjj = rr & 15;     // j within slice
    float bias_g[4]; float wz_r = 0.f; float c_reg = 0.f;
    if (roleA || roleB) {
        #pragma unroll
        for (int g = 0; g < 4; ++g) {
            long grow = (long)(g * HH + j0 + rjj);
            bias_g[g] = b_ih[grow] + b_hh[grow];
        }
        wz_r = W_z[j0 + rjj];
    }

    // consumer gather mapping: 2 tagged ull per thread (2 batches x 256 j)
    const int cb    = tid >> 7;              // 0..1
    const int cjj   = (tid & 127) << 1;      // 0..254 even
    const int cphys = cjj + ((cjj >> 5) << 2);

    int tokA_nxt, tokB_nxt;
    float4 xA[8], xB[8];
    float4 accA[4], accB[4];

    {   // ---- prologue: x(0) -> phase1(0); tokens for t=1 ----
        int tA0 = sent[0 * NB + b0A + bp];
        int tB0 = sent[0 * NB + b0B + bp];
        const float4* ea = (const float4*)(emb + (long)tA0 * EE + kbase);
        const float4* eb = (const float4*)(emb + (long)tB0 * EE + kbase);
        #pragma unroll
        for (int mi = 0; mi < 8; ++mi) { xA[mi] = ea[mi]; xB[mi] = eb[mi]; }
        tokA_nxt = sent[1 * NB + b0A + bp];
        tokB_nxt = sent[1 * NB + b0B + bp];
        #pragma unroll
        for (int i = 0; i < 4; ++i) {
            accA[i] = make_float4(0.f, 0.f, 0.f, 0.f);
            accB[i] = make_float4(0.f, 0.f, 0.f, 0.f);
        }
        #pragma unroll
        for (int mi = 0; mi < 8; ++mi) {
            float4 xa = xA[mi], xb = xB[mi];
            #pragma unroll
            for (int i = 0; i < 4; ++i) {
                float4 w = wih_r[i * 8 + mi];
                accA[i].x += w.x * xa.x; accA[i].y += w.y * xa.y;
                accA[i].z += w.z * xa.z; accA[i].w += w.w * xa.w;
                accB[i].x += w.x * xb.x; accB[i].y += w.y * xb.y;
                accB[i].z += w.z * xb.z; accB[i].w += w.w * xb.w;
            }
        }
    }

    unsigned long long va0 = 0, va1 = 0, vb0 = 0, vb1 = 0;

    for (int t = 0; t < TT; ++t) {
        const bool pf = (t + 1 < TT);

        // ================= A half (group gA, step t) =================
        if (t > 0) {
            const unsigned want = (unsigned)t;
            unsigned long long* hp =
                hbuf + ((size_t)(((t - 1) & 1) * NB + b0A + cb)) * HH + cjj;
            while ((unsigned)(va0 >> 32) != want)
                va0 = __hip_atomic_load(hp + 0, __ATOMIC_RELAXED, __HIP_MEMORY_SCOPE_AGENT);
            while ((unsigned)(va1 >> 32) != want)
                va1 = __hip_atomic_load(hp + 1, __ATOMIC_RELAXED, __HIP_MEMORY_SCOPE_AGENT);
            union { unsigned u; float f; } c0, c1;
            c0.u = (unsigned)va0; c1.u = (unsigned)va1;
            *(float2*)(&h_swA[cb * XLD + cphys]) = make_float2(c0.f, c1.f);
            // pre-issue B's h(t-1) tags (published one half ago)
            unsigned long long* hpb =
                hbuf + ((size_t)(((t - 1) & 1) * NB + b0B + cb)) * HH + cjj;
            vb0 = __hip_atomic_load(hpb + 0, __ATOMIC_RELAXED, __HIP_MEMORY_SCOPE_AGENT);
            vb1 = __hip_atomic_load(hpb + 1, __ATOMIC_RELAXED, __HIP_MEMORY_SCOPE_AGENT);
        }
        if (pf) {  // issue x_A(t+1) emb loads (consumed post-B2a)
            const float4* ea = (const float4*)(emb + (long)tokA_nxt * EE + kbase);
            #pragma unroll
            for (int mi = 0; mi < 8; ++mi) xA[mi] = ea[mi];
            tokA_nxt = sent[(t + 2 < TT ? t + 2 : TT - 1) * NB + b0A + bp];
        }
        __syncthreads();   // B1a: h_swA ready

        if (t > 0) {       // W_hh partials into accA
            #pragma unroll
            for (int mi = 0; mi < 8; ++mi) {
                float4 hv = *(const float4*)(&h_swA[bp * XLD + kc * 36 + mi * 4]);
                #pragma unroll
                for (int i = 0; i < 4; ++i) {
                    float4 w = whh_r[i * 8 + mi];
                    accA[i].x += w.x * hv.x; accA[i].y += w.y * hv.y;
                    accA[i].z += w.z * hv.z; accA[i].w += w.w * hv.w;
                }
            }
        }
        {   // horizontal add -> red_s
            float4 v;
            v.x = (accA[0].x + accA[0].y) + (accA[0].z + accA[0].w);
            v.y = (accA[1].x + accA[1].y) + (accA[1].z + accA[1].w);
            v.z = (accA[2].x + accA[2].y) + (accA[2].z + accA[2].w);
            v.w = (accA[3].x + accA[3].y) + (accA[3].z + accA[3].w);
            *(float4*)(&red_s[kc * 132 + bp * 64 + rg * 4]) = v;
        }
        __syncthreads();   // B2a: red_s ready

        {   // A epilogue on wave0 lanes<32; all waves then do phase1(t+1)
            float pvA = 0.f;
            if (roleA) {
                float sg[4];
                #pragma unroll
                for (int g = 0; g < 4; ++g) {
                    float s = bias_g[g];
                    #pragma unroll
                    for (int k2 = 0; k2 < 8; ++k2)
                        s += red_s[k2 * 132 + rb * 64 + g * 16 + rjj];
                    sg[g] = s;
                }
                float cn = sigf(sg[1]) * c_reg + sigf(sg[0]) * tanhf(sg[2]);
                float hn = sigf(sg[3]) * tanhf(cn);
                c_reg = cn;
                __hip_atomic_store(
                    hbuf + ((size_t)((t & 1) * NB + b0A + rb)) * HH + j0 + rjj,
                    packh((unsigned)(t + 1), hn),
                    __ATOMIC_RELAXED, __HIP_MEMORY_SCOPE_AGENT);
                pvA = hn * wz_r;
            }
            if (wv == 0) {  // sequential-order part sum via in-wave shfl
                float s = 0.f;
                #pragma unroll
                for (int i2 = 0; i2 < 16; ++i2)
                    s += __shfl(pvA, ((lane - 32) & 1) * 16 + i2, 64);
                if (lane == 32 || lane == 33)
                    part[((size_t)t * PJ + js) * NB + b0A + (lane - 32)] = s;
            }
        }
        if (pf) {   // phase1 A(t+1): pure-register FMAs (overlaps epilogue)
            #pragma unroll
            for (int i = 0; i < 4; ++i) accA[i] = make_float4(0.f, 0.f, 0.f, 0.f);
            #pragma unroll
            for (int mi = 0; mi < 8; ++mi) {
                float4 xa = xA[mi];
                #pragma unroll
                for (int i = 0; i < 4; ++i) {
                    float4 w = wih_r[i * 8 + mi];
                    accA[i].x += w.x * xa.x; accA[i].y += w.y * xa.y;
                    accA[i].z += w.z * xa.z; accA[i].w += w.w * xa.w;
                }
            }
        }

        // ================= B half (group gB, step t) =================
        if (t > 0) {
            const unsigned want = (unsigned)t;
            unsigned long long* hp =
                hbuf + ((size_t)(((t - 1) & 1) * NB + b0B + cb)) * HH + cjj;
            while ((unsigned)(vb0 >> 32) != want)
                vb0 = __hip_atomic_load(hp + 0, __ATOMIC_RELAXED, __HIP_MEMORY_SCOPE_AGENT);
            while ((unsigned)(vb1 >> 32) != want)
                vb1 = __hip_atomic_load(hp + 1, __ATOMIC_RELAXED, __HIP_MEMORY_SCOPE_AGENT);
            union { unsigned u; float f; } c0, c1;
            c0.u = (unsigned)vb0; c1.u = (unsigned)vb1;
            *(float2*)(&h_swB[cb * XLD + cphys]) = make_float2(c0.f, c1.f);
        }
        if (pf) {   // pre-issue A's h(t) tags (published this A-half)
            unsigned long long* hpa =
                hbuf + ((size_t)((t & 1) * NB + b0A + cb)) * HH + cjj;
            va0 = __hip_atomic_load(hpa + 0, __ATOMIC_RELAXED, __HIP_MEMORY_SCOPE_AGENT);
            va1 = __hip_atomic_load(hpa + 1, __ATOMIC_RELAXED, __HIP_MEMORY_SCOPE_AGENT);
            // issue x_B(t+1) emb loads
            const float4* eb = (const float4*)(emb + (long)tokB_nxt * EE + kbase);
            #pragma unroll
            for (int mi = 0; mi < 8; ++mi) xB[mi] = eb[mi];
            tokB_nxt = sent[(t + 2 < TT ? t + 2 : TT - 1) * NB + b0B + bp];
        }
        __syncthreads();   // B1b: h_swB ready

        if (t > 0) {
            #pragma unroll
            for (int mi = 0; mi < 8; ++mi) {
                float4 hv = *(const float4*)(&h_swB[bp * XLD + kc * 36 + mi * 4]);
                #pragma unroll
                for (int i = 0; i < 4; ++i) {
                    float4 w = whh_r[i * 8 + mi];
                    accB[i].x += w.x * hv.x; accB[i].y += w.y * hv.y;
                    accB[i].z += w.z * hv.z; accB[i].w += w.w * hv.w;
                }
            }
        }
        {
            float4 v;
            v.x = (accB[0].x + accB[0].y) + (accB[0].z + accB[0].w);
            v.y = (accB[1].x + accB[1].y) + (accB[1].z + accB[1].w);
            v.z = (accB[2].x + accB[2].y) + (accB[2].z + accB[2].w);
            v.w = (accB[3].x + accB[3].y) + (accB[3].z + accB[3].w);
            *(float4*)(&red_s[kc * 132 + bp * 64 + rg * 4]) = v;
        }
        __syncthreads();   // B2b: red_s ready

        {   // B epilogue on wave1 lanes<32
            float pvB = 0.f;
            if (roleB) {
                float sg[4];
                #pragma unroll
                for (int g = 0; g < 4; ++g) {
                    float s = bias_g[g];
                    #pragma unroll
                    for (int k2 = 0; k2 < 8; ++k2)
                        s += red_s[k2 * 132 + rb * 64 + g * 16 + rjj];
                    sg[g] = s;
                }
                float cn = sigf(sg[1]) * c_reg + sigf(sg[0]) * tanhf(sg[2]);
                float hn = sigf(sg[3]) * tanhf(cn);
                c_reg = cn;
                __hip_atomic_store(
                    hbuf + ((size_t)((t & 1) * NB + b0B + rb)) * HH + j0 + rjj,
                    packh((unsigned)(t + 1), hn),
                    __ATOMIC_RELAXED, __HIP_MEMORY_SCOPE_AGENT);
                pvB = hn * wz_r;
            }
            if (wv == 1) {
                float s = 0.f;
                #pragma unroll
                for (int i2 = 0; i2 < 16; ++i2)
                    s += __shfl(pvB, ((lane - 32) & 1) * 16 + i2, 64);
                if (lane == 32 || lane == 33)
                    part[((size_t)t * PJ + js) * NB + b0B + (lane - 32)] = s;
            }
        }
        if (pf) {   // phase1 B(t+1)
            #pragma unroll
            for (int i = 0; i < 4; ++i) accB[i] = make_float4(0.f, 0.f, 0.f, 0.f);
            #pragma unroll
            for (int mi = 0; mi < 8; ++mi) {
                float4 xb = xB[mi];
                #pragma unroll
                for (int i = 0; i < 4; ++i) {
                    float4 w = wih_r[i * 8 + mi];
                    accB[i].x += w.x * xb.x; accB[i].y += w.y * xb.y;
                    accB[i].z += w.z * xb.z; accB[i].w += w.w * xb.w;
                }
            }
        }
    }
}

__global__ void pz_kernel(const float* __restrict__ part,
                          const float* __restrict__ noise,
                          const float* __restrict__ b_z,
                          float* __restrict__ out)
{
    int idx = blockIdx.x * blockDim.x + threadIdx.x;  // t*64 + b
    if (idx >= TT * NB) return;
    int t = idx >> 6, b = idx & 63;
    float s = b_z[0];
    #pragma unroll
    for (int jg = 0; jg < PJ; ++jg) s += part[(t * PJ + jg) * NB + b];
    float pz = 1.f / (1.f + expf(-s));
    out[idx] = pz;
    out[TT * NB + idx] = (noise[idx] < pz) ? 1.f : 0.f;
}

// One block per batch column: stable compaction of tokens where z==1.
__global__ void compact_kernel(const int* __restrict__ sent,
                               const float* __restrict__ zbuf,
                               float* __restrict__ rat,
                               float* __restrict__ zsz)
{
    __shared__ float rat_s[TT];
    __shared__ int scan_s[256];
    int b = blockIdx.x, tid = threadIdx.x;
    int zloc[8];
    int base = tid * 8;
    int c = 0;
    #pragma unroll
    for (int i = 0; i < 8; ++i) {
        zloc[i] = (zbuf[(base + i) * NB + b] != 0.f) ? 1 : 0;
        c += zloc[i];
    }
    scan_s[tid] = c;
    for (int i = tid; i < TT; i += 256) rat_s[i] = 0.f;
    __syncthreads();
    for (int off = 1; off < 256; off <<= 1) {
        int v = scan_s[tid];
        int add = (tid >= off) ? scan_s[tid - off] : 0;
        __syncthreads();
        scan_s[tid] = v + add;
        __syncthreads();
    }
    int total = scan_s[255];
    int pos = scan_s[tid] - c;  // exclusive prefix
    #pragma unroll
    for (int i = 0; i < 8; ++i) {
        if (zloc[i]) { rat_s[pos] = (float)sent[(base + i) * NB + b]; ++pos; }
    }
    __syncthreads();
    for (int i = tid; i < TT; i += 256) rat[i * NB + b] = rat_s[i];
    if (tid == 0) zsz[b] = (float)total;
}

extern "C" void kernel_launch(void* const* d_in, const int* in_sizes, int n_in,
                              void* d_out, int out_size, void* d_ws, size_t ws_size,
                              hipStream_t stream)
{
    const int*   sent  = (const int*)d_in[0];
    const float* noise = (const float*)d_in[1];
    const float* emb   = (const float*)d_in[2];
    const float* W_ih  = (const float*)d_in[3];
    const float* W_hh  = (const float*)d_in[4];
    const float* b_ih  = (const float*)d_in[5];
    const float* b_hh  = (const float*)d_in[6];
    const float* W_z   = (const float*)d_in[7];
    const float* b_z   = (const float*)d_in[8];
    float* out = (float*)d_out;

    char* ws = (char*)d_ws;
    unsigned long long* hbuf = (unsigned long long*)ws;     // 2*64*256*8 = 256 KB
    float* part = (float*)(ws + 262144);                    // 2048*16*64*4 = 8 MB

    // tags must start != any expected tag (1..2048)
    hipMemsetAsync(hbuf, 0, 2 * NB * HH * sizeof(unsigned long long), stream);

    lstm_kernel<<<256, 256, 0, stream>>>(sent, emb, W_ih, W_hh, b_ih, b_hh, W_z,
                                         hbuf, part);
    pz_kernel<<<(TT * NB) / 256, 256, 0, stream>>>(part, noise, b_z, out);
    compact_kernel<<<NB, 256, 0, stream>>>(sent, out + TT * NB,
                                           out + 2 * TT * NB, out + 3 * TT * NB);
}

// Round 2
// 6936.533 us; speedup vs baseline: 2.1065x; 2.1065x over previous
//
#include <hip/hip_runtime.h>
#include <math.h>

#define TT 2048
#define NB 64
#define EE 256
#define HH 256
#define NGRP 16   // batch groups (4 batches each)
#define PJ 16     // j-partitions (WGs) per group
#define JW 16     // j per WG
#define XLD 288   // swizzled row: 256 + 4 pad per 32 floats

__device__ __forceinline__ float sigf(float x) { return 1.f / (1.f + expf(-x)); }

__device__ __forceinline__ unsigned long long packh(unsigned tag, float v) {
    union { float f; unsigned u; } c; c.f = v;
    return ((unsigned long long)tag << 32) | (unsigned long long)c.u;
}

// R8: R6 structure (single context, LDS x-staging, VGPR weights) with the
// serial tail cut: barriers 4->2 per step. Wave0 owns the full epilogue
// (reduce + gates + tagged publish + shfl part-sum) in registers while
// waves 1-3 run ahead into phase1(t+1). Spin loads for h_{t-1} are hoisted
// above phase1 so their latency hides under the FMA block. All per-value
// fp op orders identical to R6 (bitwise-identical outputs).
__global__ __launch_bounds__(256, 1)
void lstm_kernel(const int* __restrict__ sent, const float* __restrict__ emb,
                 const float* __restrict__ W_ih, const float* __restrict__ W_hh,
                 const float* __restrict__ b_ih, const float* __restrict__ b_hh,
                 const float* __restrict__ W_z,
                 unsigned long long* __restrict__ hbuf,
                 float* __restrict__ part)
{
    __shared__ float x_sw[4 * XLD];
    __shared__ float h_sw[4 * XLD];
    __shared__ float red_s[7 * 260 + 256];  // [kc]*260 + [b]*64 + row
    __shared__ int   tok_ns[4];

    const int tid  = threadIdx.x;
    // XCD-clustering swizzle (heuristic, as R6)
    const int xcd  = blockIdx.x & 7;
    const int slot = blockIdx.x >> 3;       // 0..31
    const int grp  = xcd * 2 + (slot >> 4); // 0..15 batch group
    const int jgrp = slot & 15;             // 0..15 j-slice
    const int b0   = grp << 2;
    const int j0   = jgrp << 4;

    const int wv    = tid >> 6;
    const int lane  = tid & 63;
    const int rg    = lane >> 2;            // 0..15 row-group (4 rows)
    const int klow  = lane & 3;
    const int kc    = (wv >> 1) * 4 + klow; // 0..7  k-chunk (32 floats)
    const int bp    = wv & 1;               // batch pair
    const int kbase = kc << 5;

    // ---- W chunks -> VGPRs (one-time global read; no LDS copy) ----
    float4 wih_r[32], whh_r[32];
    #pragma unroll
    for (int i = 0; i < 4; ++i) {
        int lr_i = rg * 4 + i;
        long grow = (long)((lr_i >> 4) * HH + j0 + (lr_i & 15));
        const float4* wi = (const float4*)(W_ih + grow * EE + kbase);
        const float4* wh = (const float4*)(W_hh + grow * EE + kbase);
        #pragma unroll
        for (int mi = 0; mi < 8; ++mi) {
            wih_r[i * 8 + mi] = wi[mi];
            whh_r[i * 8 + mi] = wh[mi];
        }
    }

    // ---- wave0 epilogue state (one (b,jj) output per lane) ----
    const int eb  = lane >> 4;   // batch 0..3
    const int ejj = lane & 15;   // j within slice
    float bias_g[4]; float wz_r = 0.f; float c_reg = 0.f;
    if (wv == 0) {
        #pragma unroll
        for (int g = 0; g < 4; ++g)
            bias_g[g] = b_ih[g * HH + j0 + ejj] + b_hh[g * HH + j0 + ejj];
        wz_r = W_z[j0 + ejj];
    }

    // consumer fill mapping: this thread loads h[(b0+cb)][cj..cj+3]
    const int cb    = tid >> 6;
    const int cj    = (tid & 63) << 2;
    const int cphys = cj + ((cj >> 5) << 2);

    if (tid < 4) tok_ns[tid] = sent[0 * NB + b0 + tid];
    __syncthreads();
    {   // prologue: stage x for t=0 (swizzled)
        int b  = tid >> 6;
        int e4 = tid & 63;
        float4 xv = ((const float4*)(emb + (long)tok_ns[b] * EE))[e4];
        int phys = 4 * e4 + ((e4 >> 3) << 2);
        *(float4*)(&x_sw[b * XLD + phys]) = xv;
    }
    __syncthreads();

    for (int t = 0; t < TT; ++t) {
        const bool pf = (t + 1 < TT);

        // ---- pre-issue tagged loads of h_{t-1} (latency hides under phase1)
        unsigned long long v0 = 0, v1 = 0, v2 = 0, v3 = 0;
        unsigned long long* hp =
            hbuf + ((size_t)(((t - 1) & 1) * NB + b0 + cb)) * HH + cj;
        if (t > 0) {
            v0 = __hip_atomic_load(hp + 0, __ATOMIC_RELAXED, __HIP_MEMORY_SCOPE_AGENT);
            v1 = __hip_atomic_load(hp + 1, __ATOMIC_RELAXED, __HIP_MEMORY_SCOPE_AGENT);
            v2 = __hip_atomic_load(hp + 2, __ATOMIC_RELAXED, __HIP_MEMORY_SCOPE_AGENT);
            v3 = __hip_atomic_load(hp + 3, __ATOMIC_RELAXED, __HIP_MEMORY_SCOPE_AGENT);
        }

        // ---- phase 1: x partials (x_sw staged previous iteration) ----
        float4 acc4[4][2];
        #pragma unroll
        for (int i = 0; i < 4; ++i)
            #pragma unroll
            for (int j = 0; j < 2; ++j)
                acc4[i][j] = make_float4(0.f, 0.f, 0.f, 0.f);

        #pragma unroll
        for (int j = 0; j < 2; ++j) {
            const float* xb = &x_sw[(2 * bp + j) * XLD + kc * 36];
            #pragma unroll
            for (int mi = 0; mi < 8; ++mi) {
                float4 xv4 = *(const float4*)(xb + mi * 4);
                #pragma unroll
                for (int i = 0; i < 4; ++i) {
                    float4 w = wih_r[i * 8 + mi];
                    acc4[i][j].x += w.x * xv4.x; acc4[i][j].y += w.y * xv4.y;
                    acc4[i][j].z += w.z * xv4.z; acc4[i][j].w += w.w * xv4.w;
                }
            }
        }

        if (tid < 4 && pf) tok_ns[tid] = sent[(t + 1) * NB + b0 + tid];

        // ---- phase 2a: spin-check pre-issued loads, fill h_sw ----
        if (t > 0) {
            const unsigned want = (unsigned)t;   // h_{t-1} carries tag t
            while ((unsigned)(v0 >> 32) != want)
                v0 = __hip_atomic_load(hp + 0, __ATOMIC_RELAXED, __HIP_MEMORY_SCOPE_AGENT);
            while ((unsigned)(v1 >> 32) != want)
                v1 = __hip_atomic_load(hp + 1, __ATOMIC_RELAXED, __HIP_MEMORY_SCOPE_AGENT);
            while ((unsigned)(v2 >> 32) != want)
                v2 = __hip_atomic_load(hp + 2, __ATOMIC_RELAXED, __HIP_MEMORY_SCOPE_AGENT);
            while ((unsigned)(v3 >> 32) != want)
                v3 = __hip_atomic_load(hp + 3, __ATOMIC_RELAXED, __HIP_MEMORY_SCOPE_AGENT);
            union { unsigned u; float f; } c0, c1, c2, c3;
            c0.u = (unsigned)v0; c1.u = (unsigned)v1;
            c2.u = (unsigned)v2; c3.u = (unsigned)v3;
            *(float4*)(&h_sw[cb * XLD + cphys]) =
                make_float4(c0.f, c1.f, c2.f, c3.f);
        }
        __syncthreads();   // B1: h_sw ready; x_sw reads done; tok_ns ready

        float4 xv;         // emb prefetch (completes behind h-FMAs)
        if (pf) {
            int b  = tid >> 6;
            int e4 = tid & 63;
            xv = ((const float4*)(emb + (long)tok_ns[b] * EE))[e4];
        }

        // ---- phase 2b: h partials into same accumulators ----
        if (t > 0) {
            #pragma unroll
            for (int j = 0; j < 2; ++j) {
                const float* hb = &h_sw[(2 * bp + j) * XLD + kc * 36];
                #pragma unroll
                for (int mi = 0; mi < 8; ++mi) {
                    float4 hv4 = *(const float4*)(hb + mi * 4);
                    #pragma unroll
                    for (int i = 0; i < 4; ++i) {
                        float4 w = whh_r[i * 8 + mi];
                        acc4[i][j].x += w.x * hv4.x; acc4[i][j].y += w.y * hv4.y;
                        acc4[i][j].z += w.z * hv4.z; acc4[i][j].w += w.w * hv4.w;
                    }
                }
            }
        }
        // horizontal-add partials, write to reduction scratch
        #pragma unroll
        for (int j = 0; j < 2; ++j) {
            int b = 2 * bp + j;
            float4 v;
            v.x = (acc4[0][j].x + acc4[0][j].y) + (acc4[0][j].z + acc4[0][j].w);
            v.y = (acc4[1][j].x + acc4[1][j].y) + (acc4[1][j].z + acc4[1][j].w);
            v.z = (acc4[2][j].x + acc4[2][j].y) + (acc4[2][j].z + acc4[2][j].w);
            v.w = (acc4[3][j].x + acc4[3][j].y) + (acc4[3][j].z + acc4[3][j].w);
            *(float4*)(&red_s[kc * 260 + b * 64 + rg * 4]) = v;
        }
        if (pf) {          // stage next x (x_sw readers finished pre-B1)
            int b  = tid >> 6;
            int e4 = tid & 63;
            int phys = 4 * e4 + ((e4 >> 3) << 2);
            *(float4*)(&x_sw[b * XLD + phys]) = xv;
        }
        __syncthreads();   // B2: red_s ready; x_sw staged for t+1

        // ---- epilogue: wave0 only (reduce + gates + publish + part) ----
        // Waves 1-3 fall through to phase1(t+1); their red_s writes for
        // t+1 happen after B1(t+1), which wave0 reaches only after its
        // red_s reads here -- no hazard.
        if (wv == 0) {
            float sg[4];
            #pragma unroll
            for (int g = 0; g < 4; ++g) {
                float s = bias_g[g];
                #pragma unroll
                for (int k2 = 0; k2 < 8; ++k2)
                    s += red_s[k2 * 260 + eb * 64 + g * 16 + ejj];
                sg[g] = s;
            }
            float cn = sigf(sg[1]) * c_reg + sigf(sg[0]) * tanhf(sg[2]);
            float hn = sigf(sg[3]) * tanhf(cn);
            c_reg = cn;
            __hip_atomic_store(
                hbuf + ((size_t)((t & 1) * NB + b0 + eb)) * HH + j0 + ejj,
                packh((unsigned)(t + 1), hn),
                __ATOMIC_RELAXED, __HIP_MEMORY_SCOPE_AGENT);
            float pv = hn * wz_r;
            // sequential-order part sum (matches R6's p_s loop order)
            float s = 0.f;
            #pragma unroll
            for (int i2 = 0; i2 < 16; ++i2)
                s += __shfl(pv, (lane & 48) + i2, 64);
            if (ejj == 0)
                part[((size_t)t * PJ + jgrp) * NB + b0 + eb] = s;
        }
    }
}

__global__ void pz_kernel(const float* __restrict__ part,
                          const float* __restrict__ noise,
                          const float* __restrict__ b_z,
                          float* __restrict__ out)
{
    int idx = blockIdx.x * blockDim.x + threadIdx.x;  // t*64 + b
    if (idx >= TT * NB) return;
    int t = idx >> 6, b = idx & 63;
    float s = b_z[0];
    #pragma unroll
    for (int jg = 0; jg < PJ; ++jg) s += part[(t * PJ + jg) * NB + b];
    float pz = 1.f / (1.f + expf(-s));
    out[idx] = pz;
    out[TT * NB + idx] = (noise[idx] < pz) ? 1.f : 0.f;
}

// One block per batch column: stable compaction of tokens where z==1.
__global__ void compact_kernel(const int* __restrict__ sent,
                               const float* __restrict__ zbuf,
                               float* __restrict__ rat,
                               float* __restrict__ zsz)
{
    __shared__ float rat_s[TT];
    __shared__ int scan_s[256];
    int b = blockIdx.x, tid = threadIdx.x;
    int zloc[8];
    int base = tid * 8;
    int c = 0;
    #pragma unroll
    for (int i = 0; i < 8; ++i) {
        zloc[i] = (zbuf[(base + i) * NB + b] != 0.f) ? 1 : 0;
        c += zloc[i];
    }
    scan_s[tid] = c;
    for (int i = tid; i < TT; i += 256) rat_s[i] = 0.f;
    __syncthreads();
    for (int off = 1; off < 256; off <<= 1) {
        int v = scan_s[tid];
        int add = (tid >= off) ? scan_s[tid - off] : 0;
        __syncthreads();
        scan_s[tid] = v + add;
        __syncthreads();
    }
    int total = scan_s[255];
    int pos = scan_s[tid] - c;  // exclusive prefix
    #pragma unroll
    for (int i = 0; i < 8; ++i) {
        if (zloc[i]) { rat_s[pos] = (float)sent[(base + i) * NB + b]; ++pos; }
    }
    __syncthreads();
    for (int i = tid; i < TT; i += 256) rat[i * NB + b] = rat_s[i];
    if (tid == 0) zsz[b] = (float)total;
}

extern "C" void kernel_launch(void* const* d_in, const int* in_sizes, int n_in,
                              void* d_out, int out_size, void* d_ws, size_t ws_size,
                              hipStream_t stream)
{
    const int*   sent  = (const int*)d_in[0];
    const float* noise = (const float*)d_in[1];
    const float* emb   = (const float*)d_in[2];
    const float* W_ih  = (const float*)d_in[3];
    const float* W_hh  = (const float*)d_in[4];
    const float* b_ih  = (const float*)d_in[5];
    const float* b_hh  = (const float*)d_in[6];
    const float* W_z   = (const float*)d_in[7];
    const float* b_z   = (const float*)d_in[8];
    float* out = (float*)d_out;

    char* ws = (char*)d_ws;
    unsigned long long* hbuf = (unsigned long long*)ws;     // 2*64*256*8 = 256 KB
    float* part = (float*)(ws + 262144);                    // 2048*16*64*4 = 8 MB

    // tags must start != any expected tag (1..2048)
    hipMemsetAsync(hbuf, 0, 2 * NB * HH * sizeof(unsigned long long), stream);

    lstm_kernel<<<256, 256, 0, stream>>>(sent, emb, W_ih, W_hh, b_ih, b_hh, W_z,
                                         hbuf, part);
    pz_kernel<<<(TT * NB) / 256, 256, 0, stream>>>(part, noise, b_z, out);
    compact_kernel<<<NB, 256, 0, stream>>>(sent, out + TT * NB,
                                           out + 2 * TT * NB, out + 3 * TT * NB);
}

// Round 3
// 5627.755 us; speedup vs baseline: 2.5963x; 1.2326x over previous
//
#include <hip/hip_runtime.h>
#include <math.h>

#define TT 2048
#define NB 64
#define EE 256
#define HH 256
#define PJ 16    // j-partitions recorded in part[] (unchanged layout)
#define XLD 288  // swizzled row: 256 + 4 pad per 32 floats
#define RS1 280  // red_s kc stride   (280 mod 32 = 24)
#define RS2 72   // red_s batch stride (72 mod 32 = 8 -> 2-way = free on reduce)

__device__ __forceinline__ float sigf(float x) { return 1.f / (1.f + expf(-x)); }

__device__ __forceinline__ unsigned long long packh(unsigned tag, float v) {
    union { float f; unsigned u; } c; c.f = v;
    return ((unsigned long long)tag << 32) | (unsigned long long)c.u;
}

// R9: 512-thread WG (8 waves, 2/SIMD) for LDS-latency hiding -- the R6/R8
// structure was 1 wave/SIMD so every lgkmcnt stall was dead time. Per-thread
// task: 2 rows x 2 batches x 32k -> weight regs 256->128, total ~190 VGPR
// (launch_bounds(512,2) enforces 2 waves/SIMD). 2 barriers/step. Wave0 owns
// reduce+gates+publish (bank-free red_s strides); part-sum done by wave1 one
// step later from p_s (off the critical path -- R8's shfl chain removed).
// Staging/prefetch on waves 4-7. Per-value fp op order identical to R6.
__global__ __launch_bounds__(512, 2)
void lstm_kernel(const int* __restrict__ sent, const float* __restrict__ emb,
                 const float* __restrict__ W_ih, const float* __restrict__ W_hh,
                 const float* __restrict__ b_ih, const float* __restrict__ b_hh,
                 const float* __restrict__ W_z,
                 unsigned long long* __restrict__ hbuf,
                 float* __restrict__ part)
{
    __shared__ float x_sw[4 * XLD];
    __shared__ float h_sw[4 * XLD];
    __shared__ float red_s[8 * RS1];
    __shared__ float p_s[64];
    __shared__ int   tok_ns[4];

    const int tid  = threadIdx.x;
    // XCD-clustering swizzle (heuristic, as R6)
    const int xcd  = blockIdx.x & 7;
    const int slot = blockIdx.x >> 3;       // 0..31
    const int grp  = xcd * 2 + (slot >> 4); // 0..15 batch group
    const int jgrp = slot & 15;             // 0..15 j-slice
    const int b0   = grp << 2;
    const int j0   = jgrp << 4;

    const int wv    = tid >> 6;             // 0..7
    const int lane  = tid & 63;
    const int bp    = wv & 1;               // batch pair (0: b0,b1  1: b2,b3)
    const int kc    = (wv >> 1) * 2 + (lane & 1);  // 0..7 k-chunk (32 floats)
    const int rg    = lane >> 1;            // 0..31 row-group (2 rows)
    const int kbase = kc << 5;

    // ---- W chunks -> VGPRs: 2 rows x 8 float4 per matrix = 128 VGPRs ----
    float4 wih_r[16], whh_r[16];
    #pragma unroll
    for (int i = 0; i < 2; ++i) {
        int lr = rg * 2 + i;                          // row 0..63
        long grow = (long)((lr >> 4) * HH + j0 + (lr & 15));
        const float4* wi = (const float4*)(W_ih + grow * EE + kbase);
        const float4* wh = (const float4*)(W_hh + grow * EE + kbase);
        #pragma unroll
        for (int mi = 0; mi < 8; ++mi) {
            wih_r[i * 8 + mi] = wi[mi];
            whh_r[i * 8 + mi] = wh[mi];
        }
    }

    // ---- wave0 epilogue state (one (b,jj) output per lane) ----
    const int eb  = lane >> 4;   // batch 0..3
    const int ejj = lane & 15;   // j within slice
    float bias_g[4]; float wz_r = 0.f; float c_reg = 0.f;
    if (wv == 0) {
        #pragma unroll
        for (int g = 0; g < 4; ++g)
            bias_g[g] = b_ih[g * HH + j0 + ejj] + b_hh[g * HH + j0 + ejj];
        wz_r = W_z[j0 + ejj];
    }

    // consumer fill mapping: 2 tagged ull per thread (4 batches x 256 j)
    const int cb    = tid >> 7;              // 0..3
    const int cj    = (tid & 127) << 1;      // 0..254 even
    const int cphys = cj + ((cj >> 5) << 2);

    // staging role: waves 4-7 (keeps wave0's critical path lean)
    const int st = tid - 256;

    if (st >= 0 && st < 4) tok_ns[st] = sent[0 * NB + b0 + st];
    __syncthreads();
    if (st >= 0) {   // prologue: stage x for t=0 (swizzled)
        int b = st >> 6, e4 = st & 63;
        float4 xv0 = ((const float4*)(emb + (long)tok_ns[b] * EE))[e4];
        int phys = 4 * e4 + ((e4 >> 3) << 2);
        *(float4*)(&x_sw[b * XLD + phys]) = xv0;
    }
    __syncthreads();

    for (int t = 0; t < TT; ++t) {
        const bool pf = (t + 1 < TT);

        // ---- phase 1: x partials (x_sw staged previous iteration) ----
        float4 acc[2][2];   // [row i][batch jb]
        #pragma unroll
        for (int i = 0; i < 2; ++i)
            #pragma unroll
            for (int j = 0; j < 2; ++j)
                acc[i][j] = make_float4(0.f, 0.f, 0.f, 0.f);

        #pragma unroll
        for (int jb = 0; jb < 2; ++jb) {
            const float* xb = &x_sw[(2 * bp + jb) * XLD + kc * 36];
            #pragma unroll
            for (int mi = 0; mi < 8; ++mi) {
                float4 xv4 = *(const float4*)(xb + mi * 4);
                #pragma unroll
                for (int i = 0; i < 2; ++i) {
                    float4 w = wih_r[i * 8 + mi];
                    acc[i][jb].x += w.x * xv4.x; acc[i][jb].y += w.y * xv4.y;
                    acc[i][jb].z += w.z * xv4.z; acc[i][jb].w += w.w * xv4.w;
                }
            }
        }

        if (st >= 0 && st < 4 && pf) tok_ns[st] = sent[(t + 1) * NB + b0 + st];

        // ---- spin-consume h_{t-1} (publish->consume slack is large;
        //      usually hits first try), fill h_sw ----
        if (t > 0) {
            const unsigned want = (unsigned)t;   // h_{t-1} carries tag t
            unsigned long long* hp =
                hbuf + ((size_t)(((t - 1) & 1) * NB + b0 + cb)) * HH + cj;
            unsigned long long v0, v1;
            v0 = __hip_atomic_load(hp + 0, __ATOMIC_RELAXED, __HIP_MEMORY_SCOPE_AGENT);
            v1 = __hip_atomic_load(hp + 1, __ATOMIC_RELAXED, __HIP_MEMORY_SCOPE_AGENT);
            while ((unsigned)(v0 >> 32) != want)
                v0 = __hip_atomic_load(hp + 0, __ATOMIC_RELAXED, __HIP_MEMORY_SCOPE_AGENT);
            while ((unsigned)(v1 >> 32) != want)
                v1 = __hip_atomic_load(hp + 1, __ATOMIC_RELAXED, __HIP_MEMORY_SCOPE_AGENT);
            union { unsigned u; float f; } c0, c1;
            c0.u = (unsigned)v0; c1.u = (unsigned)v1;
            *(float2*)(&h_sw[cb * XLD + cphys]) = make_float2(c0.f, c1.f);
        }
        __syncthreads();   // B1: h_sw ready; x_sw(t) reads done; tok_ns ready

        // part-sum for step t-1: wave1 lanes 0..3, off the critical path
        // (p_s written by wave0 pre-B1; next p_s write is post-B2)
        if (t > 0 && wv == 1 && lane < 4) {
            float s = 0.f;
            #pragma unroll
            for (int jj = 0; jj < 16; ++jj) s += p_s[lane * 16 + jj];
            part[((size_t)(t - 1) * PJ + jgrp) * NB + b0 + lane] = s;
        }

        float4 xv;         // emb prefetch on staging waves (hides under phase2b)
        if (st >= 0 && pf) {
            int b = st >> 6, e4 = st & 63;
            xv = ((const float4*)(emb + (long)tok_ns[b] * EE))[e4];
        }

        // ---- phase 2b: h partials into same accumulators ----
        if (t > 0) {
            #pragma unroll
            for (int jb = 0; jb < 2; ++jb) {
                const float* hb = &h_sw[(2 * bp + jb) * XLD + kc * 36];
                #pragma unroll
                for (int mi = 0; mi < 8; ++mi) {
                    float4 hv4 = *(const float4*)(hb + mi * 4);
                    #pragma unroll
                    for (int i = 0; i < 2; ++i) {
                        float4 w = whh_r[i * 8 + mi];
                        acc[i][jb].x += w.x * hv4.x; acc[i][jb].y += w.y * hv4.y;
                        acc[i][jb].z += w.z * hv4.z; acc[i][jb].w += w.w * hv4.w;
                    }
                }
            }
        }
        // horizontal-add partials, write to reduction scratch (float2 per b)
        #pragma unroll
        for (int jb = 0; jb < 2; ++jb) {
            int b = 2 * bp + jb;
            float2 v;
            v.x = (acc[0][jb].x + acc[0][jb].y) + (acc[0][jb].z + acc[0][jb].w);
            v.y = (acc[1][jb].x + acc[1][jb].y) + (acc[1][jb].z + acc[1][jb].w);
            *(float2*)(&red_s[kc * RS1 + b * RS2 + rg * 2]) = v;
        }
        if (st >= 0 && pf) {   // stage next x (x_sw readers finished pre-B1)
            int b = st >> 6, e4 = st & 63;
            int phys = 4 * e4 + ((e4 >> 3) << 2);
            *(float4*)(&x_sw[b * XLD + phys]) = xv;
        }
        __syncthreads();   // B2: red_s ready; x_sw staged for t+1

        // ---- epilogue: wave0 only (reduce + gates + publish + p_s) ----
        // Waves 1-7 fall through to phase1(t+1); their red_s/x_sw writes for
        // t+1 happen after B1(t+1), which wave0 reaches only after its reads.
        if (wv == 0) {
            float sg[4];
            #pragma unroll
            for (int g = 0; g < 4; ++g) {
                float s = bias_g[g];
                #pragma unroll
                for (int k2 = 0; k2 < 8; ++k2)
                    s += red_s[k2 * RS1 + eb * RS2 + g * 16 + ejj];
                sg[g] = s;
            }
            float cn = sigf(sg[1]) * c_reg + sigf(sg[0]) * tanhf(sg[2]);
            float hn = sigf(sg[3]) * tanhf(cn);
            c_reg = cn;
            __hip_atomic_store(
                hbuf + ((size_t)((t & 1) * NB + b0 + eb)) * HH + j0 + ejj,
                packh((unsigned)(t + 1), hn),
                __ATOMIC_RELAXED, __HIP_MEMORY_SCOPE_AGENT);
            p_s[lane] = hn * wz_r;
        }
    }

    // final part-sum (t = TT-1)
    __syncthreads();
    if (wv == 1 && lane < 4) {
        float s = 0.f;
        #pragma unroll
        for (int jj = 0; jj < 16; ++jj) s += p_s[lane * 16 + jj];
        part[((size_t)(TT - 1) * PJ + jgrp) * NB + b0 + lane] = s;
    }
}

__global__ void pz_kernel(const float* __restrict__ part,
                          const float* __restrict__ noise,
                          const float* __restrict__ b_z,
                          float* __restrict__ out)
{
    int idx = blockIdx.x * blockDim.x + threadIdx.x;  // t*64 + b
    if (idx >= TT * NB) return;
    int t = idx >> 6, b = idx & 63;
    float s = b_z[0];
    #pragma unroll
    for (int jg = 0; jg < PJ; ++jg) s += part[(t * PJ + jg) * NB + b];
    float pz = 1.f / (1.f + expf(-s));
    out[idx] = pz;
    out[TT * NB + idx] = (noise[idx] < pz) ? 1.f : 0.f;
}

// One block per batch column: stable compaction of tokens where z==1.
__global__ void compact_kernel(const int* __restrict__ sent,
                               const float* __restrict__ zbuf,
                               float* __restrict__ rat,
                               float* __restrict__ zsz)
{
    __shared__ float rat_s[TT];
    __shared__ int scan_s[256];
    int b = blockIdx.x, tid = threadIdx.x;
    int zloc[8];
    int base = tid * 8;
    int c = 0;
    #pragma unroll
    for (int i = 0; i < 8; ++i) {
        zloc[i] = (zbuf[(base + i) * NB + b] != 0.f) ? 1 : 0;
        c += zloc[i];
    }
    scan_s[tid] = c;
    for (int i = tid; i < TT; i += 256) rat_s[i] = 0.f;
    __syncthreads();
    for (int off = 1; off < 256; off <<= 1) {
        int v = scan_s[tid];
        int add = (tid >= off) ? scan_s[tid - off] : 0;
        __syncthreads();
        scan_s[tid] = v + add;
        __syncthreads();
    }
    int total = scan_s[255];
    int pos = scan_s[tid] - c;  // exclusive prefix
    #pragma unroll
    for (int i = 0; i < 8; ++i) {
        if (zloc[i]) { rat_s[pos] = (float)sent[(base + i) * NB + b]; ++pos; }
    }
    __syncthreads();
    for (int i = tid; i < TT; i += 256) rat[i * NB + b] = rat_s[i];
    if (tid == 0) zsz[b] = (float)total;
}

extern "C" void kernel_launch(void* const* d_in, const int* in_sizes, int n_in,
                              void* d_out, int out_size, void* d_ws, size_t ws_size,
                              hipStream_t stream)
{
    const int*   sent  = (const int*)d_in[0];
    const float* noise = (const float*)d_in[1];
    const float* emb   = (const float*)d_in[2];
    const float* W_ih  = (const float*)d_in[3];
    const float* W_hh  = (const float*)d_in[4];
    const float* b_ih  = (const float*)d_in[5];
    const float* b_hh  = (const float*)d_in[6];
    const float* W_z   = (const float*)d_in[7];
    const float* b_z   = (const float*)d_in[8];
    float* out = (float*)d_out;

    char* ws = (char*)d_ws;
    unsigned long long* hbuf = (unsigned long long*)ws;     // 2*64*256*8 = 256 KB
    float* part = (float*)(ws + 262144);                    // 2048*16*64*4 = 8 MB

    // tags must start != any expected tag (1..2048)
    hipMemsetAsync(hbuf, 0, 2 * NB * HH * sizeof(unsigned long long), stream);

    lstm_kernel<<<256, 512, 0, stream>>>(sent, emb, W_ih, W_hh, b_ih, b_hh, W_z,
                                         hbuf, part);
    pz_kernel<<<(TT * NB) / 256, 256, 0, stream>>>(part, noise, b_z, out);
    compact_kernel<<<NB, 256, 0, stream>>>(sent, out + TT * NB,
                                           out + 2 * TT * NB, out + 3 * TT * NB);
}